// Round 15
// baseline (41.252 us; speedup 1.0000x reference)
//
#include <hip/hip_runtime.h>
#include <hip/hip_bf16.h>

#define NB      8           // nodes per block (half an MFMA M-tile; rest is don't-care)
#define THREADS 128         // 2 waves

// d_ws layout (float offsets)
#define WS_CST4   0         // 64 x float4 (a*g, b*g, c*g, bet)
#define WS_QUAD   256       // 6 floats: E[a2],E[b2],E[ab],E[ac],E[bc],E[c2]+eps
#define WS_DISC   272       // 18*128 floats: b2 + Ei[a]+Et[b]+Etc[c]
#define WS_W2     2576      // 16 frags * 64 lanes * 16B (bf16 W2-fragments)

typedef float f32x4  __attribute__((ext_vector_type(4)));
typedef short bf16x8 __attribute__((ext_vector_type(8)));

static __device__ __forceinline__ unsigned f2bf(float f) {
    __hip_bfloat16 h = __float2bfloat16(f);   // RNE
    return (unsigned)__builtin_bit_cast(unsigned short, h);
}

__global__ __launch_bounds__(256)
void lane_setup_kernel(const float* __restrict__ W1, const float* __restrict__ b1,
                       const float* __restrict__ gam, const float* __restrict__ bet,
                       const float* __restrict__ W2, const float* __restrict__ b2,
                       const float* __restrict__ Ei, const float* __restrict__ Et,
                       const float* __restrict__ Etc, float* __restrict__ ws)
{
    const int tid = threadIdx.x, lane = tid & 63, wv = tid >> 6;
    const int b = blockIdx.x;

    if (b == 0 && wv == 0) {
        float wx = W1[lane], wy = W1[64 + lane], bb = b1[lane];
        float sx = wx, sy = wy, sb = bb;
        #pragma unroll
        for (int m = 1; m < 64; m <<= 1) {
            sx += __shfl_xor(sx, m, 64);
            sy += __shfl_xor(sy, m, 64);
            sb += __shfl_xor(sb, m, 64);
        }
        float a = wx - sx * (1.f / 64.f);
        float bc = wy - sy * (1.f / 64.f);
        float c = bb - sb * (1.f / 64.f);
        float p0 = a * a, p1 = bc * bc, p2 = a * bc, p3 = a * c, p4 = bc * c, p5 = c * c;
        #pragma unroll
        for (int m = 1; m < 64; m <<= 1) {
            p0 += __shfl_xor(p0, m, 64); p1 += __shfl_xor(p1, m, 64);
            p2 += __shfl_xor(p2, m, 64); p3 += __shfl_xor(p3, m, 64);
            p4 += __shfl_xor(p4, m, 64); p5 += __shfl_xor(p5, m, 64);
        }
        float g = gam[lane];
        ((float4*)(ws + WS_CST4))[lane] = make_float4(a * g, bc * g, c * g, bet[lane]);
        if (lane == 0) {
            ws[WS_QUAD + 0] = p0 * (1.f / 64.f);
            ws[WS_QUAD + 1] = p1 * (1.f / 64.f);
            ws[WS_QUAD + 2] = p2 * (1.f / 64.f);
            ws[WS_QUAD + 3] = p3 * (1.f / 64.f);
            ws[WS_QUAD + 4] = p4 * (1.f / 64.f);
            ws[WS_QUAD + 5] = p5 * (1.f / 64.f) + 1e-5f;   // fold LN eps
        }
    } else if (b >= 1 && b <= 4) {
        // W2 bf16 fragments, exact per-lane MFMA layout: one frag per wave
        uint4* dst = (uint4*)(ws + WS_W2);
        int f = (b - 1) * 4 + wv;
        int c = f >> 1, kt = f & 1;
        int col = c * 16 + (lane & 15);
        int k0  = kt * 32 + (lane >> 4) * 8;
        unsigned w[4];
        #pragma unroll
        for (int j = 0; j < 4; ++j) {
            unsigned lo = f2bf(W2[(k0 + 2 * j) * 128 + col]);
            unsigned hi = f2bf(W2[(k0 + 2 * j + 1) * 128 + col]);
            w[j] = (hi << 16) | lo;
        }
        dst[f * 64 + lane] = make_uint4(w[0], w[1], w[2], w[3]);
    } else if (b == 5) {
        // disc table: all 18 (a,b,c) combos, b2 folded in
        for (int i = tid; i < 18 * 128; i += 256) {
            int combo = i >> 7, col = i & 127;
            int ai = combo / 6; int r = combo - ai * 6; int bi = r >> 1; int ci = r & 1;
            ws[WS_DISC + i] = b2[col] + Ei[ai * 128 + col] + Et[bi * 128 + col] + Etc[ci * 128 + col];
        }
    }
}

__global__ __launch_bounds__(THREADS)
void lane_node_embed_mfma(const float* __restrict__ pos,      // [N,10,2]
                          const int*   __restrict__ idx_int,  // [N]
                          const int*   __restrict__ idx_turn, // [N]
                          const int*   __restrict__ idx_tc,   // [N]
                          const float* __restrict__ ws,
                          float* __restrict__ out,            // [N,128]
                          int n_nodes)
{
    // H[node<8][p][64 bf16], 16B-chunk swizzle: chunk' = chunk ^ (node&7)
    __shared__ __align__(16) unsigned short H[NB * 9 * 64];   // 9.2 KB
    __shared__ float4 smv[NB * 9];                            // (ax, ay, is, 0)
    __shared__ int    cmb_lds[NB];

    const int tid  = threadIdx.x;
    const int lane = tid & 63;
    const int wv   = __builtin_amdgcn_readfirstlane(tid >> 6);   // 0..1
    const int blockStart = blockIdx.x * NB;

    // ---- stash first: cold pos loads issue before everything else ----
    if (tid < NB * 9) {
        int nd = tid / 9, p = tid - nd * 9;
        int gn = blockStart + nd;
        float ax = 0.f, ay = 0.f, is = 0.f;
        if (gn < n_nodes) {
            const float2* pp = (const float2*)pos + (size_t)gn * 10 + p;
            float2 q0 = pp[0], q1 = pp[1];
            float dx = q1.x - q0.x, dy = q1.y - q0.y;
            float inv = rsqrtf(fmaf(dx, dx, fmaf(dy, dy, 1e-6f)));
            dx *= inv; dy *= inv;
            float qA = ws[WS_QUAD + 0], qB = ws[WS_QUAD + 1], qC = ws[WS_QUAD + 2];
            float qD = ws[WS_QUAD + 3], qE = ws[WS_QUAD + 4], qF = ws[WS_QUAD + 5];
            float t   = fmaf(dx * dy, qC, fmaf(dx, qD, dy * qE));
            float var = fmaf(2.f, t, fmaf(dx * dx, qA, fmaf(dy * dy, qB, qF)));
            is = rsqrtf(var);
            ax = dx * is; ay = dy * is;
        }
        smv[tid] = make_float4(ax, ay, is, 0.f);
    }
    if (tid < NB) {
        int gn = blockStart + tid;
        cmb_lds[tid] = (gn < n_nodes)
            ? (idx_int[gn] * 3 + idx_turn[gn]) * 2 + idx_tc[gn] : 0;
    }

    // per-lane LN constants for this lane's k-pair (2*kl, 2*kl+1)
    const int kl   = lane & 31;
    const int half = lane >> 5;
    const float4 cstA = ((const float4*)(ws + WS_CST4))[2 * kl];
    const float4 cstB = ((const float4*)(ws + WS_CST4))[2 * kl + 1];

    __syncthreads();

    // ---- Phase A (k-pair): 4 half-waves x 2 nodes, packed b32 writes ----
    {
        const int h2   = wv * 2 + half;      // half-wave id 0..3
        const int kch  = kl >> 2;            // 16B chunk of k0=2*kl
        const int kofs = (2 * kl) & 7;       // ushort offset within chunk
        #pragma unroll
        for (int i = 0; i < 2; ++i) {
            int nd = i * 4 + h2;             // node 0..7
            int basew = nd * 576 + ((kch ^ nd) << 3) + kofs;
            #pragma unroll
            for (int p = 0; p < 9; ++p) {
                float4 t = smv[nd * 9 + p];          // broadcast read per half
                float a = fmaf(t.x, cstA.x, fmaf(t.y, cstA.y, fmaf(t.z, cstA.z, cstA.w)));
                float b = fmaf(t.x, cstB.x, fmaf(t.y, cstB.y, fmaf(t.z, cstB.z, cstB.w)));
                a = fmaxf(a, 0.f); b = fmaxf(b, 0.f);
                *(unsigned*)&H[basew + p * 64] = (f2bf(b) << 16) | f2bf(a);
            }
        }
    }
    __syncthreads();

    // ---- Phase B: M-rows = nodes (rows 8..15 are don't-care aliases) ----
    const int g   = lane >> 4;
    const int l15 = lane & 15;
    const int nd8 = l15 & 7;                 // aliased row -> valid node
    const int i0  = nd8 * 576 + ((g ^ nd8) << 3);          // kt=0 chunk
    const int i1  = nd8 * 576 + (((4 + g) ^ nd8) << 3);    // kt=1 chunk
    const int ct0 = wv * 4;                  // this wave's 4 coltiles

    const uint4* wfr = (const uint4*)(ws + WS_W2);
    const f32x4 zz = {0.f, 0.f, 0.f, 0.f};
    const bool rowsValid = (g < 2);          // C rows 4g..4g+3 are nodes only for g<2

    // combos for this lane's 4 nodes (only meaningful for g<2)
    int cjv[4];
    #pragma unroll
    for (int jj = 0; jj < 4; ++jj) cjv[jj] = cmb_lds[(g * 4 + jj) & 7];

    #pragma unroll
    for (int cg = 0; cg < 2; ++cg) {
        // stream 2 coltiles' W2 fragments (keeps VGPR low)
        bf16x8 B[2][2];
        #pragma unroll
        for (int c = 0; c < 2; ++c)
            #pragma unroll
            for (int kt = 0; kt < 2; ++kt)
                B[c][kt] = __builtin_bit_cast(bf16x8,
                               wfr[((ct0 + cg * 2 + c) * 2 + kt) * 64 + lane]);

        // disc prefetch for this group: flies under the MFMA loop
        float dvp[2][4];
        #pragma unroll
        for (int c = 0; c < 2; ++c)
            #pragma unroll
            for (int jj = 0; jj < 4; ++jj)
                dvp[c][jj] = rowsValid
                    ? ws[WS_DISC + cjv[jj] * 128 + (ct0 + cg * 2 + c) * 16 + l15] : 0.f;

        f32x4 mx0 = {-INFINITY, -INFINITY, -INFINITY, -INFINITY};
        f32x4 mx1 = mx0;
        #pragma unroll
        for (int p = 0; p < 9; ++p) {
            bf16x8 a0 = *(const bf16x8*)&H[i0 + p * 64];
            bf16x8 a1 = *(const bf16x8*)&H[i1 + p * 64];
            f32x4 t0 = __builtin_amdgcn_mfma_f32_16x16x32_bf16(a0, B[0][0], zz, 0, 0, 0);
            t0       = __builtin_amdgcn_mfma_f32_16x16x32_bf16(a1, B[0][1], t0, 0, 0, 0);
            f32x4 t1 = __builtin_amdgcn_mfma_f32_16x16x32_bf16(a0, B[1][0], zz, 0, 0, 0);
            t1       = __builtin_amdgcn_mfma_f32_16x16x32_bf16(a1, B[1][1], t1, 0, 0, 0);
            #pragma unroll
            for (int k = 0; k < 4; ++k) {
                mx0[k] = fmaxf(mx0[k], t0[k]);
                mx1[k] = fmaxf(mx1[k], t1[k]);
            }
        }

        // epilogue: C row 4g+j = node (g<2 only); col = coltile*16 + l15
        if (rowsValid) {
            #pragma unroll
            for (int c = 0; c < 2; ++c) {
                int col = (ct0 + cg * 2 + c) * 16 + l15;
                f32x4 m = (c == 0) ? mx0 : mx1;
                #pragma unroll
                for (int j = 0; j < 4; ++j) {
                    int gn = blockStart + g * 4 + j;
                    if (gn < n_nodes)
                        out[(size_t)gn * 128 + col] = m[j] + dvp[c][j];
                }
            }
        }
    }
}

extern "C" void kernel_launch(void* const* d_in, const int* in_sizes, int n_in,
                              void* d_out, int out_size, void* d_ws, size_t ws_size,
                              hipStream_t stream) {
    const float* pos  = (const float*)d_in[0];
    const int*   ii   = (const int*)  d_in[1];
    const int*   it   = (const int*)  d_in[2];
    const int*   itc  = (const int*)  d_in[3];
    const float* W1   = (const float*)d_in[4];
    const float* b1   = (const float*)d_in[5];
    const float* gam  = (const float*)d_in[6];
    const float* bet  = (const float*)d_in[7];
    const float* W2   = (const float*)d_in[8];
    const float* b2   = (const float*)d_in[9];
    const float* Ei   = (const float*)d_in[10];
    const float* Et   = (const float*)d_in[11];
    const float* Etc  = (const float*)d_in[12];
    float* out = (float*)d_out;
    float* ws  = (float*)d_ws;

    int n_nodes = in_sizes[1];                       // B*L = 65536
    int blocks  = (n_nodes + NB - 1) / NB;           // 8192

    hipLaunchKernelGGL(lane_setup_kernel, dim3(6), dim3(256), 0, stream,
                       W1, b1, gam, bet, W2, b2, Ei, Et, Etc, ws);
    hipLaunchKernelGGL(lane_node_embed_mfma, dim3(blocks), dim3(THREADS), 0, stream,
                       pos, ii, it, itc, ws, out, n_nodes);
}

// Round 17
// 30.433 us; speedup vs baseline: 1.3555x; 1.3555x over previous
//
#include <hip/hip_runtime.h>
#include <hip/hip_bf16.h>

#define NB      16          // nodes per block (one MFMA M-tile)
#define THREADS 256

// d_ws layout (float offsets)
#define WS_CST4   0         // 64 x float4 (a*g, b*g, c*g, bet)
#define WS_QUAD   256       // 6 floats: E[a2],E[b2],E[ab],E[ac],E[bc],E[c2]+eps
#define WS_DISC   272       // 18*128 floats: b2 + Ei[a]+Et[b]+Etc[c]
#define WS_W2     2576      // 16 frags * 64 lanes * 16B (bf16 B-fragments)

typedef float f32x4  __attribute__((ext_vector_type(4)));
typedef float f32x2  __attribute__((ext_vector_type(2)));
typedef short bf16x8 __attribute__((ext_vector_type(8)));

#if __has_builtin(__builtin_elementwise_fma)
static __device__ __forceinline__ f32x2 FMA2(f32x2 a, f32x2 b, f32x2 c) {
    return __builtin_elementwise_fma(a, b, c);
}
#else
static __device__ __forceinline__ f32x2 FMA2(f32x2 a, f32x2 b, f32x2 c) {
    f32x2 r; r.x = fmaf(a.x, b.x, c.x); r.y = fmaf(a.y, b.y, c.y); return r;
}
#endif

#if __has_builtin(__builtin_elementwise_max)
static __device__ __forceinline__ f32x2 MAX2(f32x2 a, f32x2 b) {
    return __builtin_elementwise_max(a, b);
}
static __device__ __forceinline__ f32x4 MAX4(f32x4 a, f32x4 b) {
    return __builtin_elementwise_max(a, b);
}
#else
static __device__ __forceinline__ f32x2 MAX2(f32x2 a, f32x2 b) {
    f32x2 r; r.x = fmaxf(a.x, b.x); r.y = fmaxf(a.y, b.y); return r;
}
static __device__ __forceinline__ f32x4 MAX4(f32x4 a, f32x4 b) {
    f32x4 r;
    r[0] = fmaxf(a[0], b[0]); r[1] = fmaxf(a[1], b[1]);
    r[2] = fmaxf(a[2], b[2]); r[3] = fmaxf(a[3], b[3]);
    return r;
}
#endif

static __device__ __forceinline__ unsigned f2bf(float f) {
    __hip_bfloat16 h = __float2bfloat16(f);   // RNE
    return (unsigned)__builtin_bit_cast(unsigned short, h);
}

__global__ __launch_bounds__(THREADS)
void lane_setup_kernel(const float* __restrict__ W1, const float* __restrict__ b1,
                       const float* __restrict__ gam, const float* __restrict__ bet,
                       const float* __restrict__ W2, const float* __restrict__ b2,
                       const float* __restrict__ Ei, const float* __restrict__ Et,
                       const float* __restrict__ Etc, float* __restrict__ ws)
{
    const int tid = threadIdx.x, lane = tid & 63, wv = tid >> 6;

    if (wv == 0) {
        float wx = W1[lane], wy = W1[64 + lane], bb = b1[lane];
        float sx = wx, sy = wy, sb = bb;
        #pragma unroll
        for (int m = 1; m < 64; m <<= 1) {
            sx += __shfl_xor(sx, m, 64);
            sy += __shfl_xor(sy, m, 64);
            sb += __shfl_xor(sb, m, 64);
        }
        float a = wx - sx * (1.f / 64.f);
        float b = wy - sy * (1.f / 64.f);
        float c = bb - sb * (1.f / 64.f);
        float p0 = a * a, p1 = b * b, p2 = a * b, p3 = a * c, p4 = b * c, p5 = c * c;
        #pragma unroll
        for (int m = 1; m < 64; m <<= 1) {
            p0 += __shfl_xor(p0, m, 64); p1 += __shfl_xor(p1, m, 64);
            p2 += __shfl_xor(p2, m, 64); p3 += __shfl_xor(p3, m, 64);
            p4 += __shfl_xor(p4, m, 64); p5 += __shfl_xor(p5, m, 64);
        }
        float g = gam[lane];
        ((float4*)(ws + WS_CST4))[lane] = make_float4(a * g, b * g, c * g, bet[lane]);
        if (lane == 0) {
            ws[WS_QUAD + 0] = p0 * (1.f / 64.f);
            ws[WS_QUAD + 1] = p1 * (1.f / 64.f);
            ws[WS_QUAD + 2] = p2 * (1.f / 64.f);
            ws[WS_QUAD + 3] = p3 * (1.f / 64.f);
            ws[WS_QUAD + 4] = p4 * (1.f / 64.f);
            ws[WS_QUAD + 5] = p5 * (1.f / 64.f) + 1e-5f;   // fold LN eps
        }
    }

    // W2 bf16 fragments, exact per-lane MFMA-B layout
    {
        uint4* dst = (uint4*)(ws + WS_W2);
        #pragma unroll
        for (int f = wv * 4; f < wv * 4 + 4; ++f) {
            int c = f >> 1, kt = f & 1;
            int col = c * 16 + (lane & 15);
            int k0  = kt * 32 + (lane >> 4) * 8;
            unsigned w[4];
            #pragma unroll
            for (int j = 0; j < 4; ++j) {
                unsigned lo = f2bf(W2[(k0 + 2 * j) * 128 + col]);
                unsigned hi = f2bf(W2[(k0 + 2 * j + 1) * 128 + col]);
                w[j] = (hi << 16) | lo;
            }
            dst[f * 64 + lane] = make_uint4(w[0], w[1], w[2], w[3]);
        }
    }

    // disc table: all 18 (a,b,c) combos, b2 folded in
    for (int i = tid; i < 18 * 128; i += THREADS) {
        int combo = i >> 7, col = i & 127;
        int ai = combo / 6; int r = combo - ai * 6; int bi = r >> 1; int ci = r & 1;
        ws[WS_DISC + i] = b2[col] + Ei[ai * 128 + col] + Et[bi * 128 + col] + Etc[ci * 128 + col];
    }
}

__global__ __launch_bounds__(THREADS)
void lane_node_embed_mfma(const float* __restrict__ pos,      // [N,10,2]
                          const int*   __restrict__ idx_int,  // [N]
                          const int*   __restrict__ idx_turn, // [N]
                          const int*   __restrict__ idx_tc,   // [N]
                          const float* __restrict__ ws,
                          float* __restrict__ out,            // [N,128]
                          int n_nodes)
{
    // H[node][p][64 bf16], 16B-chunk swizzle: chunk' = chunk ^ (node&7)
    __shared__ __align__(16) unsigned short H[NB * 9 * 64];   // 18 KB
    __shared__ float4 smv[NB * 9];              // per-row (ax, ay, is, 0)
    __shared__ int    cmb_lds[NB];

    const int tid  = threadIdx.x;
    const int lane = tid & 63;
    const int wv   = __builtin_amdgcn_readfirstlane(tid >> 6);
    const int blockStart = blockIdx.x * NB;

    // ---- stash first: cold pos loads issue before everything else ----
    if (tid < NB * 9) {
        int nd = tid / 9, p = tid - nd * 9;
        int gn = blockStart + nd;
        float ax = 0.f, ay = 0.f, is = 0.f;
        if (gn < n_nodes) {
            const float2* pp = (const float2*)pos + (size_t)gn * 10 + p;
            float2 q0 = pp[0], q1 = pp[1];
            float dx = q1.x - q0.x, dy = q1.y - q0.y;
            float inv = rsqrtf(fmaf(dx, dx, fmaf(dy, dy, 1e-6f)));
            dx *= inv; dy *= inv;
            float qA = ws[WS_QUAD + 0], qB = ws[WS_QUAD + 1], qC = ws[WS_QUAD + 2];
            float qD = ws[WS_QUAD + 3], qE = ws[WS_QUAD + 4], qF = ws[WS_QUAD + 5];
            float t   = fmaf(dx * dy, qC, fmaf(dx, qD, dy * qE));
            float var = fmaf(2.f, t, fmaf(dx * dx, qA, fmaf(dy * dy, qB, qF)));
            is = rsqrtf(var);
            ax = dx * is; ay = dy * is;
        }
        smv[tid] = make_float4(ax, ay, is, 0.f);
    }
    if (tid < NB) {
        int gn = blockStart + tid;
        cmb_lds[tid] = (gn < n_nodes)
            ? (idx_int[gn] * 3 + idx_turn[gn]) * 2 + idx_tc[gn] : 0;
    }

    // per-lane LN constants for this lane's k-pair (2*kl, 2*kl+1), packed 2-wide
    const int kl   = lane & 31;
    const int half = lane >> 5;
    const float4 cstA = ((const float4*)(ws + WS_CST4))[2 * kl];
    const float4 cstB = ((const float4*)(ws + WS_CST4))[2 * kl + 1];
    f32x2 cx, cy, cz, cw;
    cx.x = cstA.x; cx.y = cstB.x;
    cy.x = cstA.y; cy.y = cstB.y;
    cz.x = cstA.z; cz.y = cstB.z;
    cw.x = cstA.w; cw.y = cstB.w;

    // B fragments for this wave's 2 coltiles (prepacked, coalesced)
    const int ct0 = wv * 2;
    const uint4* wfr = (const uint4*)(ws + WS_W2);
    bf16x8 Bfr[2][2];
    #pragma unroll
    for (int c = 0; c < 2; ++c)
        #pragma unroll
        for (int kt = 0; kt < 2; ++kt)
            Bfr[c][kt] = __builtin_bit_cast(bf16x8, wfr[((ct0 + c) * 2 + kt) * 64 + lane]);

    __syncthreads();

    // ---- Phase A (k-pair): halves handle 2 nodes/iter, packed math + b32 writes ----
    {
        const int kch  = kl >> 2;            // 16B chunk of k0=2*kl
        const int kofs = (2 * kl) & 7;       // ushort offset within chunk
        f32x2 zero2; zero2.x = 0.f; zero2.y = 0.f;
        #pragma unroll
        for (int i = 0; i < 2; ++i) {
            int nd = wv * 4 + 2 * i + half;
            int basew = nd * 576 + ((kch ^ (nd & 7)) << 3) + kofs;
            #pragma unroll
            for (int p = 0; p < 9; ++p) {
                float4 t = smv[nd * 9 + p];          // broadcast read per half
                f32x2 tz; tz.x = t.z; tz.y = t.z;
                f32x2 ty; ty.x = t.y; ty.y = t.y;
                f32x2 tx; tx.x = t.x; tx.y = t.x;
                f32x2 h = FMA2(tz, cz, cw);          // same assoc as R11
                h = FMA2(ty, cy, h);
                h = FMA2(tx, cx, h);
                h = MAX2(h, zero2);                   // ReLU
                *(unsigned*)&H[basew + p * 64] = (f2bf(h.y) << 16) | f2bf(h.x);
            }
        }
    }
    __syncthreads();

    // ---- Phase B: M-rows = 16 nodes; packed max over p between MFMAs ----
    const int g   = lane >> 4;
    const int l15 = lane & 15;
    const int sr  = l15 & 7;
    const int i0  = l15 * 576 + ((g ^ sr) << 3);          // kt=0 chunk
    const int i1  = l15 * 576 + (((4 + g) ^ sr) << 3);    // kt=1 chunk

    // prefetch disc values: loads fly under the MFMA loop
    int cjv[4];
    #pragma unroll
    for (int jj = 0; jj < 4; ++jj) cjv[jj] = cmb_lds[g * 4 + jj];
    float dvp[2][4];
    #pragma unroll
    for (int c = 0; c < 2; ++c)
        #pragma unroll
        for (int jj = 0; jj < 4; ++jj)
            dvp[c][jj] = ws[WS_DISC + cjv[jj] * 128 + (ct0 + c) * 16 + l15];

    const f32x4 zz = {0.f, 0.f, 0.f, 0.f};
    f32x4 mx0, mx1;
    {   // p = 0 peeled: initializes mx directly (no -INF init / first max)
        bf16x8 a0 = *(const bf16x8*)&H[i0];
        bf16x8 a1 = *(const bf16x8*)&H[i1];
        mx0 = __builtin_amdgcn_mfma_f32_16x16x32_bf16(a0, Bfr[0][0], zz, 0, 0, 0);
        mx0 = __builtin_amdgcn_mfma_f32_16x16x32_bf16(a1, Bfr[0][1], mx0, 0, 0, 0);
        mx1 = __builtin_amdgcn_mfma_f32_16x16x32_bf16(a0, Bfr[1][0], zz, 0, 0, 0);
        mx1 = __builtin_amdgcn_mfma_f32_16x16x32_bf16(a1, Bfr[1][1], mx1, 0, 0, 0);
    }
    #pragma unroll
    for (int p = 1; p < 9; ++p) {
        bf16x8 a0 = *(const bf16x8*)&H[i0 + p * 64];
        bf16x8 a1 = *(const bf16x8*)&H[i1 + p * 64];
        f32x4 t0 = __builtin_amdgcn_mfma_f32_16x16x32_bf16(a0, Bfr[0][0], zz, 0, 0, 0);
        t0       = __builtin_amdgcn_mfma_f32_16x16x32_bf16(a1, Bfr[0][1], t0, 0, 0, 0);
        f32x4 t1 = __builtin_amdgcn_mfma_f32_16x16x32_bf16(a0, Bfr[1][0], zz, 0, 0, 0);
        t1       = __builtin_amdgcn_mfma_f32_16x16x32_bf16(a1, Bfr[1][1], t1, 0, 0, 0);
        mx0 = MAX4(mx0, t0);   // v_pk_max_f32 x2
        mx1 = MAX4(mx1, t1);
    }

    // ---- epilogue: pure add + store (disc already in regs) ----
    #pragma unroll
    for (int c = 0; c < 2; ++c) {
        int col = (ct0 + c) * 16 + l15;
        f32x4 m = (c == 0) ? mx0 : mx1;
        #pragma unroll
        for (int j = 0; j < 4; ++j) {
            int gn = blockStart + g * 4 + j;
            if (gn < n_nodes)
                out[(size_t)gn * 128 + col] = m[j] + dvp[c][j];
        }
    }
}

extern "C" void kernel_launch(void* const* d_in, const int* in_sizes, int n_in,
                              void* d_out, int out_size, void* d_ws, size_t ws_size,
                              hipStream_t stream) {
    const float* pos  = (const float*)d_in[0];
    const int*   ii   = (const int*)  d_in[1];
    const int*   it   = (const int*)  d_in[2];
    const int*   itc  = (const int*)  d_in[3];
    const float* W1   = (const float*)d_in[4];
    const float* b1   = (const float*)d_in[5];
    const float* gam  = (const float*)d_in[6];
    const float* bet  = (const float*)d_in[7];
    const float* W2   = (const float*)d_in[8];
    const float* b2   = (const float*)d_in[9];
    const float* Ei   = (const float*)d_in[10];
    const float* Et   = (const float*)d_in[11];
    const float* Etc  = (const float*)d_in[12];
    float* out = (float*)d_out;
    float* ws  = (float*)d_ws;

    int n_nodes = in_sizes[1];                       // B*L = 65536
    int blocks  = (n_nodes + NB - 1) / NB;           // 4096

    hipLaunchKernelGGL(lane_setup_kernel, dim3(1), dim3(THREADS), 0, stream,
                       W1, b1, gam, bet, W2, b2, Ei, Et, Etc, ws);
    hipLaunchKernelGGL(lane_node_embed_mfma, dim3(blocks), dim3(THREADS), 0, stream,
                       pos, ii, it, itc, ws, out, n_nodes);
}